// Round 2
// baseline (406.045 us; speedup 1.0000x reference)
//
#include <hip/hip_runtime.h>

#define Bn 256
#define Sn 4096
#define Fn 64
#define TCOST 0.0003f
#define INIT_CAP 500.0f

// Output layout (floats):
//   equity      : [B, S+1]        offset 0
//   positions   : [B, S+1, 3]     offset B*(S+1)
//   predictions : [B, S]          offset B*(S+1)*4
//   position_sz : [B]             offset B*(S+1)*4 + B*S
#define EQ_OFF   0
#define POS_OFF  (Bn * (Sn + 1))
#define PRED_OFF (Bn * (Sn + 1) * 4)
#define PSZ_OFF  (PRED_OFF + Bn * Sn)

// Fused kernel: one block per batch element b.
//   Phase 1 (streaming): 16 lanes cooperatively process one (b,s) row
//     (16 x float4 = 64 features, one contiguous 1 KiB load per wave).
//     Gumbel-softmax epilogue on the sub==0 lane; q0/q1/q2/ret_part go to
//     LDS (no global staging round-trip), pos/pred go to global (outputs).
//   Phase 2 (scan): chunked factor product + Hillis-Steele product-scan
//     entirely out of LDS; coalesced equity write-out.
#define TB   1024
#define CHB  (Sn / TB)             // 4 steps per thread in the scan
#define LQ   (Sn + 1)              // 1-based step index 0..Sn
#define PADi(i) ((i) + ((i) >> 3)) // pad every 8 to break stride-4 conflicts
#define LQP  (LQ + (LQ >> 3) + 1)

__global__ __launch_bounds__(TB) void trishot_fused(
    const float* __restrict__ feat,     // [B, S, F]
    const float* __restrict__ w,        // [F]
    const float* __restrict__ p_lt, const float* __restrict__ p_st,
    const float* __restrict__ p_bps, const float* __restrict__ p_cs,
    const float* __restrict__ p_vi, const float* __restrict__ p_vct,
    const float* __restrict__ p_vst,
    const float* __restrict__ gumbel,   // [S, B, 3]
    float* __restrict__ out)
{
    const int b    = blockIdx.x;
    const int tid  = threadIdx.x;
    const int lane = tid & 63;
    const int sub  = lane & 15;         // position within 16-lane row group
    const int gid  = tid >> 4;          // row group 0..63 within block

    __shared__ float sq0[LQP];
    __shared__ float sq1[LQP];
    __shared__ float sq2[LQP];
    __shared__ float srp[LQP];
    __shared__ float sc[TB];

    const float LT = *p_lt, ST = *p_st, BPS = *p_bps, CS = *p_cs,
                VI = *p_vi, VCT = *p_vct, VST = *p_vst;

    // each lane's slice of the weight vector (constant across rows)
    const float4 wv = ((const float4*)w)[sub];

    float* pos = out + POS_OFF;

    // ---------------- phase 1: predictions + probs ----------------
#pragma unroll 4
    for (int it = 0; it < Sn / (TB / 16); ++it) {   // 64 iterations
        const int s = it * (TB / 16) + gid;
        const size_t row = (size_t)b * Sn + s;
        const float4 fv = ((const float4*)feat)[row * 16 + sub];

        float x = fv.x * wv.x + fv.y * wv.y + fv.z * wv.z + fv.w * wv.w;
        // butterfly sum within each 16-lane group (masks < 16 stay in-group)
        x += __shfl_xor(x, 1);
        x += __shfl_xor(x, 2);
        x += __shfl_xor(x, 4);
        x += __shfl_xor(x, 8);

        if (sub == 0) {
            // this lane's float4 is elems 0..3 of the row: mom,vix,dvix,mret
            const float p = 1.0f / (1.0f + __expf(-x));
            const float mom = fv.x, vix = fv.y, dvix = fv.z, mret = fv.w;

            const float ss = fabsf(p - 0.5f) * 2.0f;
            const bool collapse = (dvix < -VCT) && (vix < 30.0f);
            const bool spike    = (dvix >  VST) && (vix > 20.0f);
            float psz = fminf(fmaxf(BPS + CS * ss, 0.2f), 1.0f);
            if (collapse || spike) psz *= (1.0f + VI);

            const bool lp = ((p >= LT) && (mom > 0.0f)) || collapse;
            const bool sp = ((p <= ST) && (mom < 0.0f)) || spike;
            const float l0 = lp ? 1.0f : -10.0f;
            const float l1 = sp ? 1.0f : -10.0f;
            const float l2 = (!lp && !sp) ? 1.0f : -10.0f;

            const float* g = gumbel + ((size_t)s * Bn + b) * 3;
            const float z0 = l0 + g[0], z1 = l1 + g[1], z2 = l2 + g[2];
            const float zm = fmaxf(z0, fmaxf(z1, z2));
            const float e0 = __expf(z0 - zm), e1 = __expf(z1 - zm),
                        e2 = __expf(z2 - zm);
            const float inv = 1.0f / (e0 + e1 + e2);
            const float q0 = e0 * inv, q1 = e1 * inv, q2 = e2 * inv;

            out[PRED_OFF + row] = p;

            const size_t prow = ((size_t)b * (Sn + 1) + s + 1) * 3;
            pos[prow + 0] = q0;
            pos[prow + 1] = q1;
            pos[prow + 2] = q2;

            sq0[PADi(s + 1)] = q0;
            sq1[PADi(s + 1)] = q1;
            sq2[PADi(s + 1)] = q2;
            srp[PADi(s + 1)] = psz * (q0 - q1) * mret;

            if (s == Sn - 1) {
                out[PSZ_OFF + b] = psz;   // last-step position size
            }
        }
    }

    if (tid == 0) {
        sq0[PADi(0)] = 0.0f;
        sq1[PADi(0)] = 0.0f;
        sq2[PADi(0)] = 1.0f;
        const size_t p0row = (size_t)b * (Sn + 1) * 3;
        pos[p0row + 0] = 0.0f;
        pos[p0row + 1] = 0.0f;
        pos[p0row + 2] = 1.0f;
        out[EQ_OFF + (size_t)b * (Sn + 1)] = INIT_CAP;
    }
    __syncthreads();

    // ---------------- phase 2: equity prefix-product scan ----------------
    const int t0 = tid * CHB;
    float prev0 = sq0[PADi(t0)];
    float prev1 = sq1[PADi(t0)];
    float prev2 = sq2[PADi(t0)];

    float f[CHB];
    float lprod = 1.0f;
#pragma unroll
    for (int i = 0; i < CHB; ++i) {
        const int s = t0 + i + 1;
        const float c0 = sq0[PADi(s)], c1 = sq1[PADi(s)], c2 = sq2[PADi(s)];
        const float pc = fabsf(c0 - prev0) + fabsf(c1 - prev1)
                       + fabsf(c2 - prev2);
        const float fac = 1.0f + srp[PADi(s)] - pc * TCOST;
        f[i] = fac;
        lprod *= fac;
        prev0 = c0; prev1 = c1; prev2 = c2;
    }
    sc[tid] = lprod;
    __syncthreads();

    // Hillis-Steele inclusive product-scan over TB chunk products
#pragma unroll
    for (int off = 1; off < TB; off <<= 1) {
        const float mine  = sc[tid];
        const float other = (tid >= off) ? sc[tid - off] : 1.0f;
        __syncthreads();
        sc[tid] = mine * other;
        __syncthreads();
    }

    float* eq = out + EQ_OFF + (size_t)b * (Sn + 1);
    float eqv = INIT_CAP * ((tid > 0) ? sc[tid - 1] : 1.0f);
#pragma unroll
    for (int i = 0; i < CHB; ++i) {
        eqv *= f[i];
        eq[t0 + i + 1] = eqv;
    }
}

extern "C" void kernel_launch(void* const* d_in, const int* in_sizes, int n_in,
                              void* d_out, int out_size, void* d_ws, size_t ws_size,
                              hipStream_t stream) {
    const float* feat   = (const float*)d_in[0];
    const float* w      = (const float*)d_in[1];
    const float* lt     = (const float*)d_in[2];
    const float* st     = (const float*)d_in[3];
    const float* bps    = (const float*)d_in[4];
    const float* cs     = (const float*)d_in[5];
    const float* vi     = (const float*)d_in[6];
    const float* vct    = (const float*)d_in[7];
    const float* vst    = (const float*)d_in[8];
    const float* gumbel = (const float*)d_in[9];
    float* out = (float*)d_out;

    trishot_fused<<<Bn, TB, 0, stream>>>(
        feat, w, lt, st, bps, cs, vi, vct, vst, gumbel, out);
}

// Round 3
// 388.114 us; speedup vs baseline: 1.0462x; 1.0462x over previous
//
#include <hip/hip_runtime.h>

#define Bn 256
#define Sn 4096
#define Fn 64
#define TCOST 0.0003f
#define INIT_CAP 500.0f

// Output layout (floats):
//   equity      : [B, S+1]        offset 0
//   positions   : [B, S+1, 3]     offset B*(S+1)
//   predictions : [B, S]          offset B*(S+1)*4
//   position_sz : [B]             offset B*(S+1)*4 + B*S
#define EQ_OFF   0
#define POS_OFF  (Bn * (Sn + 1))
#define PRED_OFF (Bn * (Sn + 1) * 4)
#define PSZ_OFF  (PRED_OFF + Bn * Sn)

// Kernel A (identical to the round-1 version that measured best):
// wave-cooperative — 16 lanes own one (b,s) row (16 x float4 = 64 floats),
// 4 rows per wave, 64 rows per 256-thread block. Every feature load is one
// contiguous 1 KiB wave access. No LDS -> 8 blocks/CU = 32 waves/CU.
#define ROWS_PB 64

__global__ __launch_bounds__(256) void trishot_fwd(
    const float* __restrict__ feat,     // [B, S, F]
    const float* __restrict__ w,        // [F]
    const float* __restrict__ p_lt, const float* __restrict__ p_st,
    const float* __restrict__ p_bps, const float* __restrict__ p_cs,
    const float* __restrict__ p_vi, const float* __restrict__ p_vct,
    const float* __restrict__ p_vst,
    const float* __restrict__ gumbel,   // [S, B, 3]
    float* __restrict__ out)
{
    const int tid  = threadIdx.x;
    const int lane = tid & 63;
    const int wave = tid >> 6;          // 0..3
    const int sub  = lane & 15;         // position within 16-lane row group
    const int grp  = lane >> 4;         // 0..3: row within wave

    const float LT = *p_lt, ST = *p_st, BPS = *p_bps, CS = *p_cs,
                VI = *p_vi, VCT = *p_vct, VST = *p_vst;

    const float4 wv = ((const float4*)w)[sub];

    const size_t r0 = (size_t)blockIdx.x * ROWS_PB;

#pragma unroll
    for (int pass = 0; pass < ROWS_PB / 16; ++pass) {
        const size_t row = r0 + (size_t)pass * 16 + (size_t)(wave * 4 + grp);
        const float4 fv = ((const float4*)feat)[row * 16 + sub];

        float x = fv.x * wv.x + fv.y * wv.y + fv.z * wv.z + fv.w * wv.w;
        // butterfly sum within each 16-lane group (masks < 16 stay in-group)
        x += __shfl_xor(x, 1);
        x += __shfl_xor(x, 2);
        x += __shfl_xor(x, 4);
        x += __shfl_xor(x, 8);

        if (sub == 0) {
            // this lane's float4 is elems 0..3 of the row: mom,vix,dvix,mret
            const int b = (int)(row >> 12);           // S = 4096 = 2^12
            const int s = (int)(row & (Sn - 1));

            const float p = 1.0f / (1.0f + __expf(-x));
            const float mom = fv.x, vix = fv.y, dvix = fv.z, mret = fv.w;

            const float ss = fabsf(p - 0.5f) * 2.0f;
            const bool collapse = (dvix < -VCT) && (vix < 30.0f);
            const bool spike    = (dvix >  VST) && (vix > 20.0f);
            float psz = fminf(fmaxf(BPS + CS * ss, 0.2f), 1.0f);
            if (collapse || spike) psz *= (1.0f + VI);

            const bool lp = ((p >= LT) && (mom > 0.0f)) || collapse;
            const bool sp = ((p <= ST) && (mom < 0.0f)) || spike;
            const float l0 = lp ? 1.0f : -10.0f;
            const float l1 = sp ? 1.0f : -10.0f;
            const float l2 = (!lp && !sp) ? 1.0f : -10.0f;

            const float* g = gumbel + ((size_t)s * Bn + b) * 3;
            const float z0 = l0 + g[0], z1 = l1 + g[1], z2 = l2 + g[2];
            const float zm = fmaxf(z0, fmaxf(z1, z2));
            const float e0 = __expf(z0 - zm), e1 = __expf(z1 - zm),
                        e2 = __expf(z2 - zm);
            const float inv = 1.0f / (e0 + e1 + e2);
            const float q0 = e0 * inv, q1 = e1 * inv, q2 = e2 * inv;

            out[PRED_OFF + row] = p;

            const size_t prow = ((size_t)b * (Sn + 1) + s + 1) * 3;
            float* pos = out + POS_OFF;
            pos[prow + 0] = q0;
            pos[prow + 1] = q1;
            pos[prow + 2] = q2;

            // stage ret_part into equity cell [b][s+1] (kernel B overwrites)
            out[EQ_OFF + (size_t)b * (Sn + 1) + s + 1] = psz * (q0 - q1) * mret;

            if (s == 0) {
                const size_t p0row = (size_t)b * (Sn + 1) * 3;
                pos[p0row + 0] = 0.0f;
                pos[p0row + 1] = 0.0f;
                pos[p0row + 2] = 1.0f;
            }
            if (s == Sn - 1) {
                out[PSZ_OFF + b] = psz;   // last-step position size
            }
        }
    }
}

// Kernel B: one block per batch element, 1024 threads. Coalesced factor
// computation into padded LDS, then hierarchical shuffle product-scan:
//   per-thread 4-factor product -> wave shfl_up scan (no barriers)
//   -> 16 wave totals scanned by wave 0 -> combine. 3 barriers total
// (vs 18 for Hillis-Steele over 512).
#define TB   1024
#define CHB  (Sn / TB)              // 4
#define PADi(i) ((i) + ((i) >> 3))  // pad every 8 to break power-of-2 strides

__global__ __launch_bounds__(TB) void trishot_scan(float* __restrict__ out)
{
    const int b = blockIdx.x;
    const int j = threadIdx.x;
    const int lane = j & 63;
    const int wid  = j >> 6;        // 0..15

    float* eq = out + EQ_OFF + (size_t)b * (Sn + 1);
    const float* pos = out + POS_OFF + (size_t)b * (Sn + 1) * 3;

    __shared__ float sfac[Sn + (Sn >> 3)];   // 4608 floats, padded
    __shared__ float swave[16];

    // phase 1: coalesced factor computation (rows i and i+1 -> factor i)
    for (int i = j; i < Sn; i += TB) {
        const float a0 = pos[i * 3 + 0];
        const float a1 = pos[i * 3 + 1];
        const float a2 = pos[i * 3 + 2];
        const float c0 = pos[i * 3 + 3];
        const float c1 = pos[i * 3 + 4];
        const float c2 = pos[i * 3 + 5];
        const float pc = fabsf(c0 - a0) + fabsf(c1 - a1) + fabsf(c2 - a2);
        const float rp = eq[i + 1];          // staged ret_part
        sfac[PADi(i)] = 1.0f + rp - pc * TCOST;
    }
    __syncthreads();

    // phase 2: per-thread chunk product
    const int t0 = j * CHB;
    const float f0 = sfac[PADi(t0 + 0)];
    const float f1 = sfac[PADi(t0 + 1)];
    const float f2 = sfac[PADi(t0 + 2)];
    const float f3 = sfac[PADi(t0 + 3)];
    const float lprod = f0 * f1 * f2 * f3;

    // wave-level inclusive product scan (64 lanes, no barriers)
    float incl = lprod;
#pragma unroll
    for (int off = 1; off < 64; off <<= 1) {
        const float v = __shfl_up(incl, off);
        if (lane >= off) incl *= v;
    }
    if (lane == 63) swave[wid] = incl;       // wave total
    __syncthreads();

    // wave 0: inclusive scan of the 16 wave totals
    if (wid == 0) {
        float wv = (lane < 16) ? swave[lane] : 1.0f;
#pragma unroll
        for (int off = 1; off < 16; off <<= 1) {
            const float v = __shfl_up(wv, off);
            if (lane >= off) wv *= v;
        }
        if (lane < 16) swave[lane] = wv;     // inclusive wave prefixes
    }
    __syncthreads();

    // phase 3: combine and write equity (per-lane 16 B chunks, contiguous
    // across lanes -> coalesced)
    const float woff = (wid > 0) ? swave[wid - 1] : 1.0f;
    float excl = __shfl_up(incl, 1);
    if (lane == 0) excl = 1.0f;
    float eqv = INIT_CAP * woff * excl;
    eqv *= f0; eq[t0 + 1] = eqv;
    eqv *= f1; eq[t0 + 2] = eqv;
    eqv *= f2; eq[t0 + 3] = eqv;
    eqv *= f3; eq[t0 + 4] = eqv;
    if (j == 0) eq[0] = INIT_CAP;
}

extern "C" void kernel_launch(void* const* d_in, const int* in_sizes, int n_in,
                              void* d_out, int out_size, void* d_ws, size_t ws_size,
                              hipStream_t stream) {
    const float* feat   = (const float*)d_in[0];
    const float* w      = (const float*)d_in[1];
    const float* lt     = (const float*)d_in[2];
    const float* st     = (const float*)d_in[3];
    const float* bps    = (const float*)d_in[4];
    const float* cs     = (const float*)d_in[5];
    const float* vi     = (const float*)d_in[6];
    const float* vct    = (const float*)d_in[7];
    const float* vst    = (const float*)d_in[8];
    const float* gumbel = (const float*)d_in[9];
    float* out = (float*)d_out;

    trishot_fwd<<<(Bn * Sn) / ROWS_PB, 256, 0, stream>>>(
        feat, w, lt, st, bps, cs, vi, vct, vst, gumbel, out);
    trishot_scan<<<Bn, TB, 0, stream>>>(out);
}

// Round 4
// 386.906 us; speedup vs baseline: 1.0495x; 1.0031x over previous
//
#include <hip/hip_runtime.h>

#define Bn 256
#define Sn 4096
#define Fn 64
#define TCOST 0.0003f
#define INIT_CAP 500.0f

// Output layout (floats):
//   equity      : [B, S+1]        offset 0
//   positions   : [B, S+1, 3]     offset B*(S+1)
//   predictions : [B, S]          offset B*(S+1)*4
//   position_sz : [B]             offset B*(S+1)*4 + B*S
#define EQ_OFF   0
#define POS_OFF  (Bn * (Sn + 1))
#define PRED_OFF (Bn * (Sn + 1) * 4)
#define PSZ_OFF  (PRED_OFF + Bn * Sn)

// Kernel A: wave-cooperative streaming (16 lanes per (b,s) row, 64 rows per
// 256-thread block, every feature load = one contiguous 1 KiB wave access).
// NEW vs round 3: the block stages its 64 q-rows in LDS, recomputes the
// boundary row s0-1 with a 16-lane pre-pass, and writes the FINAL scan
// factor f = 1 + rp - pc*TCOST into the equity cells. Kernel B then never
// touches positions (21 MB -> 8.4 MB of scan traffic).
#define ROWS_PB 64

__global__ __launch_bounds__(256) void trishot_fwd(
    const float* __restrict__ feat,     // [B, S, F]
    const float* __restrict__ w,        // [F]
    const float* __restrict__ p_lt, const float* __restrict__ p_st,
    const float* __restrict__ p_bps, const float* __restrict__ p_cs,
    const float* __restrict__ p_vi, const float* __restrict__ p_vct,
    const float* __restrict__ p_vst,
    const float* __restrict__ gumbel,   // [S, B, 3]
    float* __restrict__ out)
{
    const int tid  = threadIdx.x;
    const int lane = tid & 63;
    const int wave = tid >> 6;          // 0..3
    const int sub  = lane & 15;         // position within 16-lane row group
    const int grp  = lane >> 4;         // 0..3: row within wave

    __shared__ float sq0[ROWS_PB + 1];  // q at slots 0..64 (slot 0 = s0-1)
    __shared__ float sq1[ROWS_PB + 1];
    __shared__ float sq2[ROWS_PB + 1];
    __shared__ float srp[ROWS_PB];      // ret_part for s0..s0+63

    const float LT = *p_lt, ST = *p_st, BPS = *p_bps, CS = *p_cs,
                VI = *p_vi, VCT = *p_vct, VST = *p_vst;

    const float4 wv = ((const float4*)w)[sub];

    const size_t r0 = (size_t)blockIdx.x * ROWS_PB;
    const int b  = (int)(r0 >> 12);               // S = 4096 = 2^12
    const int s0 = (int)(r0 & (Sn - 1));          // block's first timestep

    // ---- pre-pass: q for row s0-1 (slot 0); (0,0,1) if s0 == 0 ----
    if (tid < 16) {
        float q0p = 0.0f, q1p = 0.0f, q2p = 1.0f;
        if (s0 != 0) {
            const float4 fvp = ((const float4*)feat)[(r0 - 1) * 16 + sub];
            float xp = fvp.x * wv.x + fvp.y * wv.y + fvp.z * wv.z
                     + fvp.w * wv.w;
            xp += __shfl_xor(xp, 1);
            xp += __shfl_xor(xp, 2);
            xp += __shfl_xor(xp, 4);
            xp += __shfl_xor(xp, 8);
            if (tid == 0) {
                const float p = 1.0f / (1.0f + __expf(-xp));
                const float mom = fvp.x, vix = fvp.y, dvix = fvp.z;
                const bool collapse = (dvix < -VCT) && (vix < 30.0f);
                const bool spike    = (dvix >  VST) && (vix > 20.0f);
                const bool lp = ((p >= LT) && (mom > 0.0f)) || collapse;
                const bool sp = ((p <= ST) && (mom < 0.0f)) || spike;
                const float l0 = lp ? 1.0f : -10.0f;
                const float l1 = sp ? 1.0f : -10.0f;
                const float l2 = (!lp && !sp) ? 1.0f : -10.0f;
                const float* g = gumbel + ((size_t)(s0 - 1) * Bn + b) * 3;
                const float z0 = l0 + g[0], z1 = l1 + g[1], z2 = l2 + g[2];
                const float zm = fmaxf(z0, fmaxf(z1, z2));
                const float e0 = __expf(z0 - zm), e1 = __expf(z1 - zm),
                            e2 = __expf(z2 - zm);
                const float inv = 1.0f / (e0 + e1 + e2);
                q0p = e0 * inv; q1p = e1 * inv; q2p = e2 * inv;
            }
        }
        if (tid == 0) { sq0[0] = q0p; sq1[0] = q1p; sq2[0] = q2p; }
    }

    // ---- main passes: 64 rows, epilogue on sub==0 lanes ----
#pragma unroll
    for (int pass = 0; pass < ROWS_PB / 16; ++pass) {
        const int ridx = pass * 16 + wave * 4 + grp;   // 0..63 within block
        const size_t row = r0 + (size_t)ridx;
        const float4 fv = ((const float4*)feat)[row * 16 + sub];

        float x = fv.x * wv.x + fv.y * wv.y + fv.z * wv.z + fv.w * wv.w;
        // butterfly sum within each 16-lane group (masks < 16 stay in-group)
        x += __shfl_xor(x, 1);
        x += __shfl_xor(x, 2);
        x += __shfl_xor(x, 4);
        x += __shfl_xor(x, 8);

        if (sub == 0) {
            const int s = s0 + ridx;

            const float p = 1.0f / (1.0f + __expf(-x));
            const float mom = fv.x, vix = fv.y, dvix = fv.z, mret = fv.w;

            const float ss = fabsf(p - 0.5f) * 2.0f;
            const bool collapse = (dvix < -VCT) && (vix < 30.0f);
            const bool spike    = (dvix >  VST) && (vix > 20.0f);
            float psz = fminf(fmaxf(BPS + CS * ss, 0.2f), 1.0f);
            if (collapse || spike) psz *= (1.0f + VI);

            const bool lp = ((p >= LT) && (mom > 0.0f)) || collapse;
            const bool sp = ((p <= ST) && (mom < 0.0f)) || spike;
            const float l0 = lp ? 1.0f : -10.0f;
            const float l1 = sp ? 1.0f : -10.0f;
            const float l2 = (!lp && !sp) ? 1.0f : -10.0f;

            const float* g = gumbel + ((size_t)s * Bn + b) * 3;
            const float z0 = l0 + g[0], z1 = l1 + g[1], z2 = l2 + g[2];
            const float zm = fmaxf(z0, fmaxf(z1, z2));
            const float e0 = __expf(z0 - zm), e1 = __expf(z1 - zm),
                        e2 = __expf(z2 - zm);
            const float inv = 1.0f / (e0 + e1 + e2);
            const float q0 = e0 * inv, q1 = e1 * inv, q2 = e2 * inv;

            out[PRED_OFF + row] = p;

            const size_t prow = ((size_t)b * (Sn + 1) + s + 1) * 3;
            float* pos = out + POS_OFF;
            pos[prow + 0] = q0;
            pos[prow + 1] = q1;
            pos[prow + 2] = q2;

            sq0[ridx + 1] = q0;
            sq1[ridx + 1] = q1;
            sq2[ridx + 1] = q2;
            srp[ridx]     = psz * (q0 - q1) * mret;

            if (s == Sn - 1) {
                out[PSZ_OFF + b] = psz;   // last-step position size
            }
        }
    }
    __syncthreads();

    // ---- factor write: f[s] = 1 + rp - |q[s]-q[s-1]|_1 * TCOST ----
    if (tid < ROWS_PB) {
        const float a0 = sq0[tid],     a1 = sq1[tid],     a2 = sq2[tid];
        const float c0 = sq0[tid + 1], c1 = sq1[tid + 1], c2 = sq2[tid + 1];
        const float pc = fabsf(c0 - a0) + fabsf(c1 - a1) + fabsf(c2 - a2);
        out[EQ_OFF + (size_t)b * (Sn + 1) + s0 + tid + 1] =
            1.0f + srp[tid] - pc * TCOST;
    }
}

// Kernel B: one block per batch element, 1024 threads. Reads 4096 staged
// factors (thread-exclusive 4-float slices, no LDS staging needed), does
// a hierarchical shuffle product-scan (3 barriers), writes equity in place.
#define TB   1024
#define CHB  (Sn / TB)              // 4

__global__ __launch_bounds__(TB) void trishot_scan(float* __restrict__ out)
{
    const int b = blockIdx.x;
    const int j = threadIdx.x;
    const int lane = j & 63;
    const int wid  = j >> 6;        // 0..15

    float* eq = out + EQ_OFF + (size_t)b * (Sn + 1);

    __shared__ float swave[16];

    // per-thread factors (exclusive slice -> no races with later writes)
    const int t0 = j * CHB;
    const float f0 = eq[t0 + 1];
    const float f1 = eq[t0 + 2];
    const float f2 = eq[t0 + 3];
    const float f3 = eq[t0 + 4];
    const float lprod = f0 * f1 * f2 * f3;

    // wave-level inclusive product scan (64 lanes, no barriers)
    float incl = lprod;
#pragma unroll
    for (int off = 1; off < 64; off <<= 1) {
        const float v = __shfl_up(incl, off);
        if (lane >= off) incl *= v;
    }
    if (lane == 63) swave[wid] = incl;       // wave total
    __syncthreads();

    // wave 0: inclusive scan of the 16 wave totals
    if (wid == 0) {
        float wv = (lane < 16) ? swave[lane] : 1.0f;
#pragma unroll
        for (int off = 1; off < 16; off <<= 1) {
            const float v = __shfl_up(wv, off);
            if (lane >= off) wv *= v;
        }
        if (lane < 16) swave[lane] = wv;     // inclusive wave prefixes
    }
    __syncthreads();

    // combine and write equity (consecutive 16 B thread slices -> coalesced)
    const float woff = (wid > 0) ? swave[wid - 1] : 1.0f;
    float excl = __shfl_up(incl, 1);
    if (lane == 0) excl = 1.0f;
    float eqv = INIT_CAP * woff * excl;
    eqv *= f0; eq[t0 + 1] = eqv;
    eqv *= f1; eq[t0 + 2] = eqv;
    eqv *= f2; eq[t0 + 3] = eqv;
    eqv *= f3; eq[t0 + 4] = eqv;

    if (j == 0) {
        eq[0] = INIT_CAP;
        // positions row 0 = (0,0,1)
        float* pos0 = out + POS_OFF + (size_t)b * (Sn + 1) * 3;
        pos0[0] = 0.0f;
        pos0[1] = 0.0f;
        pos0[2] = 1.0f;
    }
}

extern "C" void kernel_launch(void* const* d_in, const int* in_sizes, int n_in,
                              void* d_out, int out_size, void* d_ws, size_t ws_size,
                              hipStream_t stream) {
    const float* feat   = (const float*)d_in[0];
    const float* w      = (const float*)d_in[1];
    const float* lt     = (const float*)d_in[2];
    const float* st     = (const float*)d_in[3];
    const float* bps    = (const float*)d_in[4];
    const float* cs     = (const float*)d_in[5];
    const float* vi     = (const float*)d_in[6];
    const float* vct    = (const float*)d_in[7];
    const float* vst    = (const float*)d_in[8];
    const float* gumbel = (const float*)d_in[9];
    float* out = (float*)d_out;

    trishot_fwd<<<(Bn * Sn) / ROWS_PB, 256, 0, stream>>>(
        feat, w, lt, st, bps, cs, vi, vct, vst, gumbel, out);
    trishot_scan<<<Bn, TB, 0, stream>>>(out);
}